// Round 1
// baseline (204.009 us; speedup 1.0000x reference)
//
#include <hip/hip_runtime.h>

// YOLOv1 loss, S=14, B=2, C=20, 30 fp32 channels/cell, 802816 cells.
// Memory-bound. Round-2 change: single per-wave LDS buffer (30720 B/block
// -> 5 blocks/CU, was 2) reused sequentially for pred then target, staged
// via global_load_lds width-16 (no VGPR round-trip, no ds_writes).
// Wave-private buffer => no __syncthreads; ordering via explicit
// s_waitcnt vmcnt(0) (DMA->LDS visible) and lgkmcnt(0) (ds_reads retired
// before the buffer is overwritten by the next DMA phase).

__global__ void zero_out_kernel(float* out) { out[0] = 0.0f; }

__device__ __forceinline__ void gll16(const void* g, void* l) {
    __builtin_amdgcn_global_load_lds(
        (const __attribute__((address_space(1))) void*)(uintptr_t)g,
        (__attribute__((address_space(3))) void*)(uintptr_t)l, 16, 0, 0);
}
__device__ __forceinline__ void gll4(const void* g, void* l) {
    __builtin_amdgcn_global_load_lds(
        (const __attribute__((address_space(1))) void*)(uintptr_t)g,
        (__attribute__((address_space(3))) void*)(uintptr_t)l, 4, 0, 0);
}

// Stage one 64-cell wave tile (7680 B, linear) global -> LDS.
// 7 x width16 covers [0,7168); 2 x width4 cover the 512 B tail.
__device__ __forceinline__ void stage_tile(const float* __restrict__ g,
                                           float* lds, int lane)
{
    const char* gb = (const char*)g;
    char* lb = (char*)lds;
    #pragma unroll
    for (int i = 0; i < 7; ++i)
        gll16(gb + i * 1024 + lane * 16, lb + i * 1024);
    gll4(gb + 7168 + lane * 4, lb + 7168);
    gll4(gb + 7424 + lane * 4, lb + 7424);
}

__global__ __launch_bounds__(256, 5) void yolo_loss_kernel(
    const float* __restrict__ pred, const float* __restrict__ target,
    float* __restrict__ out)
{
    __shared__ __align__(16) float sbuf[4][1920];  // 30720 B -> 5 blocks/CU

    const int lane = threadIdx.x & 63;
    const int wid  = threadIdx.x >> 6;
    const size_t tile0 = ((size_t)blockIdx.x * 4 + wid) * 64;  // first cell of wave tile
    const float* gp = pred   + tile0 * 30;
    const float* gt = target + tile0 * 30;
    float* sw = sbuf[wid];

    float pv[30], tv[30];

    // ---- phase P: pred -> LDS (DMA) -> own cell regs
    stage_tile(gp, sw, lane);
    asm volatile("s_waitcnt vmcnt(0)" ::: "memory");   // DMA data visible in LDS
    {
        const float2* rp = (const float2*)&sw[lane * 30];
        #pragma unroll
        for (int j = 0; j < 15; ++j) {
            float2 a = rp[j]; pv[2*j] = a.x; pv[2*j+1] = a.y;
        }
    }
    asm volatile("s_waitcnt lgkmcnt(0)" ::: "memory"); // ds_reads retired before overwrite

    // ---- phase T: target -> same LDS buffer -> regs
    stage_tile(gt, sw, lane);
    asm volatile("s_waitcnt vmcnt(0)" ::: "memory");
    {
        const float2* rt = (const float2*)&sw[lane * 30];
        #pragma unroll
        for (int j = 0; j < 15; ++j) {
            float2 b = rt[j]; tv[2*j] = b.x; tv[2*j+1] = b.y;
        }
    }

    // ---- per-cell loss (identical math to the verified round-1 kernel)
    const float invS = 1.0f / 14.0f;
    const bool obj = tv[4] > 0.0f;

    float tcx = tv[0] * invS, tcy = tv[1] * invS;
    float thw = 0.5f * tv[2], thh = 0.5f * tv[3];
    float tx1 = tcx - thw, ty1 = tcy - thh;
    float tx2 = tcx + thw, ty2 = tcy + thh;
    float area_t = (tx2 - tx1) * (ty2 - ty1);

    float iou0 = 0.0f, iou1 = 0.0f;
    #pragma unroll
    for (int b = 0; b < 2; ++b) {
        float cx = pv[5*b + 0] * invS, cy = pv[5*b + 1] * invS;
        float hw = 0.5f * pv[5*b + 2], hh = 0.5f * pv[5*b + 3];
        float x1 = cx - hw, y1 = cy - hh, x2 = cx + hw, y2 = cy + hh;
        float lx = fmaxf(x1, tx1), ly = fmaxf(y1, ty1);
        float rx = fminf(x2, tx2), ry = fminf(y2, ty2);
        float w = fmaxf(rx - lx, 0.0f), h = fmaxf(ry - ly, 0.0f);
        float inter = w * h;
        float area_p = (x2 - x1) * (y2 - y1);
        float iou = inter / (area_p + area_t - inter);
        if (b == 0) iou0 = iou; else iou1 = iou;
    }
    const bool  sel     = iou1 > iou0;          // jnp.argmax: first max wins
    const float max_iou = fmaxf(iou0, iou1);

    float local;
    if (obj) {
        float pbx = sel ? pv[5] : pv[0];
        float pby = sel ? pv[6] : pv[1];
        float pbw = sel ? pv[7] : pv[2];
        float pbh = sel ? pv[8] : pv[3];
        float pbc = sel ? pv[9] : pv[4];

        float dx = pbx - tv[0], dy = pby - tv[1];
        float loss_xy = dx*dx + dy*dy;

        float sw_ = sqrtf(pbw) - sqrtf(tv[2]);
        float sh_ = sqrtf(pbh) - sqrtf(tv[3]);
        float loss_wh = sw_*sw_ + sh_*sh_;

        float dob = pbc - max_iou;
        float loss_obj = dob * dob;

        float loss_cls = 0.0f;
        #pragma unroll
        for (int c = 0; c < 20; ++c) {
            float d = pv[10 + c] - tv[10 + c];
            loss_cls = fmaf(d, d, loss_cls);
        }
        local = 5.0f * (loss_xy + loss_wh) + loss_obj + loss_cls;
    } else {
        float d0 = pv[4] - tv[4];
        float d1 = pv[9] - tv[9];
        local = 0.5f * (d0*d0 + d1*d1);
    }

    // ---- wave-64 shuffle reduction -> block -> one atomic
    #pragma unroll
    for (int off = 32; off > 0; off >>= 1)
        local += __shfl_down(local, off, 64);

    __shared__ float wsum[4];
    if (lane == 0) wsum[wid] = local;
    __syncthreads();
    if (threadIdx.x == 0) {
        float s = wsum[0] + wsum[1] + wsum[2] + wsum[3];
        atomicAdd(out, s * (1.0f / 4096.0f));
    }
}

extern "C" void kernel_launch(void* const* d_in, const int* in_sizes, int n_in,
                              void* d_out, int out_size, void* d_ws, size_t ws_size,
                              hipStream_t stream) {
    const float* pred   = (const float*)d_in[0];
    const float* target = (const float*)d_in[1];
    float* out = (float*)d_out;

    zero_out_kernel<<<1, 1, 0, stream>>>(out);
    yolo_loss_kernel<<<3136, 256, 0, stream>>>(pred, target, out);
}